// Round 9
// baseline (315.607 us; speedup 1.0000x reference)
//
#include <hip/hip_runtime.h>
#include <hip/hip_bf16.h>

#define N_NODES 100000
#define N_EDGES 1600000
#define D 128
#define N_TILES (N_NODES / 16)   // 6250
#define NB 392                   // coarse buckets: 256 rows each (row>>8)
#define NR 100352                // NB*256 (padded row space)
#define SCAN_BLOCKS 392          // one 256-thread scan block per bucket
#define HIST_WGS 782             // scatterA WGs: 2048 edges each
#define CAP 16                   // LDS staging depth per bucket in scatterA
#define LCAP 4608                // LDS window cap in sortsum (mean 4082, +8 sigma)

typedef __bf16 bf16x8 __attribute__((ext_vector_type(8)));
typedef float  f32x4  __attribute__((ext_vector_type(4)));
typedef float  f32x2  __attribute__((ext_vector_type(2)));
typedef int    i32x2  __attribute__((ext_vector_type(2)));

// ---- K1: exact row histogram (global atomics, L2-resident) + W transpose ----
__global__ __launch_bounds__(256) void hist_transpose_kernel(
        const int* __restrict__ rows,
        const float* __restrict__ W, __bf16* __restrict__ WT,
        int* __restrict__ counts) {
    int wg = blockIdx.x;
    if (wg >= 6250) {                    // 64 transpose WGs
        int t = (wg - 6250) * 256 + threadIdx.x;
        int k = t >> 7, n = t & 127;
        WT[n * D + k] = (__bf16)W[t];
        return;
    }
    int e = wg * 256 + threadIdx.x;      // exactly N_EDGES threads
    atomicAdd(&counts[rows[e]], 1);
}

// ---- K2: per-block (256-row) reduction -> blockSums ----
__global__ __launch_bounds__(256) void block_reduce_kernel(const int* __restrict__ counts,
                                                           int* __restrict__ blockSums) {
    int i = blockIdx.x * 256 + threadIdx.x;
    int v = (i < N_NODES) ? counts[i] : 0;
#pragma unroll
    for (int off = 32; off; off >>= 1) v += __shfl_down(v, off, 64);
    __shared__ int sm[4];
    if ((threadIdx.x & 63) == 0) sm[threadIdx.x >> 6] = v;
    __syncthreads();
    if (threadIdx.x == 0) blockSums[blockIdx.x] = sm[0] + sm[1] + sm[2] + sm[3];
}

// ---- K3: exclusive scan of blockSums; also = per-bucket cursor init ----
__global__ __launch_bounds__(512) void scan_blocksums_kernel(int* __restrict__ blockSums,
                                                             int* __restrict__ coarseCur) {
    __shared__ int sm[512];
    int v = (threadIdx.x < SCAN_BLOCKS) ? blockSums[threadIdx.x] : 0;
    sm[threadIdx.x] = v;
    __syncthreads();
    for (int d = 1; d < 512; d <<= 1) {
        int t = (threadIdx.x >= (unsigned)d) ? sm[threadIdx.x - d] : 0;
        __syncthreads();
        sm[threadIdx.x] += t;
        __syncthreads();
    }
    if (threadIdx.x < SCAN_BLOCKS) {
        int ex = sm[threadIdx.x] - v;
        blockSums[threadIdx.x] = ex;     // exclusive
        coarseCur[threadIdx.x] = ex;     // scatterA claim cursors
    }
}

// ---- K4: per-block exclusive scan + block offset -> global per-row offsets ----
__global__ __launch_bounds__(256) void scan_final_kernel(const int* __restrict__ counts,
                                                         const int* __restrict__ blockSums,
                                                         int* __restrict__ offsets) {
    __shared__ int sm[256];
    int i = blockIdx.x * 256 + threadIdx.x;
    int v = (i < N_NODES) ? counts[i] : 0;
    sm[threadIdx.x] = v;
    __syncthreads();
    for (int d = 1; d < 256; d <<= 1) {
        int t = (threadIdx.x >= (unsigned)d) ? sm[threadIdx.x - d] : 0;
        __syncthreads();
        sm[threadIdx.x] += t;
        __syncthreads();
    }
    int excl = sm[threadIdx.x] - v + blockSums[blockIdx.x];
    offsets[i] = excl;                                   // i < NR always valid
    if (i == NR - 1) offsets[NR] = excl + v;             // = N_EDGES
}

// ---- GEMM: h = bf16(x) @ bf16(W) (verified since R6) ----
__global__ __launch_bounds__(256) void gemm_kernel(
        const float* __restrict__ x,
        const __bf16* __restrict__ WT,
        __bf16* __restrict__ h) {
    __shared__ __bf16 lsm[4][16][144];
    const int wave = threadIdx.x >> 6;
    const int lane = threadIdx.x & 63;
    const int tile = blockIdx.x * 4 + wave;
    if (tile >= N_TILES) return;
    const int m = lane & 15, quad = lane >> 4;
    const float* xp = x + (size_t)(tile * 16 + m) * D + quad * 8;

    f32x4 acc[8];
#pragma unroll
    for (int ct = 0; ct < 8; ++ct) acc[ct] = (f32x4)(0.0f);
#pragma unroll
    for (int kk = 0; kk < 4; ++kk) {
        f32x4 a0 = *(const f32x4*)(xp + kk * 32);
        f32x4 a1 = *(const f32x4*)(xp + kk * 32 + 4);
        bf16x8 a;
#pragma unroll
        for (int j = 0; j < 4; ++j) { a[j] = (__bf16)a0[j]; a[j + 4] = (__bf16)a1[j]; }
#pragma unroll
        for (int ct = 0; ct < 8; ++ct) {
            bf16x8 b = *(const bf16x8*)(WT + (size_t)(ct * 16 + m) * D + kk * 32 + quad * 8);
            acc[ct] = __builtin_amdgcn_mfma_f32_16x16x32_bf16(a, b, acc[ct], 0, 0, 0);
        }
    }
#pragma unroll
    for (int ct = 0; ct < 8; ++ct)
#pragma unroll
        for (int r = 0; r < 4; ++r)
            lsm[wave][quad * 4 + r][ct * 16 + m] = (__bf16)acc[ct][r];
#pragma unroll
    for (int i = 0; i < 4; ++i) {
        int rl = i * 4 + quad;
        bf16x8 vv = *(const bf16x8*)&lsm[wave][rl][m * 8];
        *(bf16x8*)(h + (size_t)(tile * 16 + rl) * D + m * 8) = vv;
    }
}

// ---- K5: staged coarse scatter. pack = ((row&255)<<17)|col, val bits ----
__global__ __launch_bounds__(256) void scatterA_kernel(
        const int* __restrict__ rows, const int* __restrict__ cols,
        const float* __restrict__ vals,
        int* __restrict__ cur, i32x2* __restrict__ svcA) {
    __shared__ i32x2 buf[NB][CAP];   // 50 KB
    __shared__ int   cnt[NB];
    for (int t = threadIdx.x; t < NB; t += 256) cnt[t] = 0;
    __syncthreads();
    int base = blockIdx.x * 2048;
    for (int it = 0; it < 8; ++it) {
        int e = base + it * 256 + threadIdx.x;
        if (e < N_EDGES) {
            int r = rows[e];
            int b = r >> 8;
            i32x2 pk;
            pk[0] = ((r & 255) << 17) | cols[e];
            pk[1] = __float_as_int(vals[e]);
            int p = atomicAdd(&cnt[b], 1);
            if (p < CAP) buf[b][p] = pk;
            else {                         // rare overflow: direct claim+store
                int g = atomicAdd(&cur[b], 1);
                svcA[g] = pk;
            }
        }
    }
    __syncthreads();
    for (int t = threadIdx.x; t < NB; t += 256) {
        int n = min(cnt[t], CAP);
        if (n > 0) {
            int g = atomicAdd(&cur[t], n);
            for (int i = 0; i < n; ++i) svcA[g + i] = buf[t][i];  // contiguous run
        }
    }
}

// ---- K6: fused in-LDS row sort + segmented sum + relu ----
// one 1024-thread WG per 256-row bucket; 16 waves x 16 rows each;
// register accumulators (NOT LDS-atomic accumulation — R7 lesson).
__global__ __launch_bounds__(1024) void sortsum_kernel(
        const __bf16* __restrict__ h, const int* __restrict__ offsets,
        const i32x2* __restrict__ svcA, float* __restrict__ out) {
    __shared__ i32x2 lbuf[LCAP];     // 36 KB
    __shared__ int   lcur[256];
    __shared__ int   lbase[257];
    const int b    = blockIdx.x;
    const int tid  = threadIdx.x;
    const int base = offsets[b * 256];
    const int n    = offsets[(b + 1) * 256] - base;

    if (tid < 256) {
        int s = offsets[b * 256 + tid] - base;
        lbase[tid] = s;
        lcur[tid]  = s;
    }
    if (tid == 0) lbase[256] = n;
    __syncthreads();

    // phase 1: scatter window into row-order inside LDS
    for (int i = tid; i < n; i += 1024) {
        i32x2 rec = svcA[base + i];
        int rl = ((unsigned)rec[0]) >> 17;
        int p = atomicAdd(&lcur[rl], 1);
        if (p < LCAP) lbuf[p] = rec;
    }
    __syncthreads();

    // phase 2: per-wave register-accumulator segsum, 4-wide gather MLP
    const int wave = tid >> 6;
    const int lane = tid & 63;
#pragma unroll 1
    for (int k = 0; k < 16; ++k) {
        int rl = wave * 16 + k;
        int gr = b * 256 + rl;
        if (gr >= N_NODES) break;
        int s = lbase[rl], e = lbase[rl + 1];

        float a0 = 0.f, b0 = 0.f, a1 = 0.f, b1 = 0.f;
        float a2 = 0.f, b2 = 0.f, a3 = 0.f, b3 = 0.f;
        int i = s;
        for (; i + 3 < e; i += 4) {
            i32x2 e0 = lbuf[i], e1 = lbuf[i + 1], e2 = lbuf[i + 2], e3 = lbuf[i + 3];
            unsigned u0 = *((const unsigned*)(h + (size_t)(e0[0] & 0x1FFFF) * D) + lane);
            unsigned u1 = *((const unsigned*)(h + (size_t)(e1[0] & 0x1FFFF) * D) + lane);
            unsigned u2 = *((const unsigned*)(h + (size_t)(e2[0] & 0x1FFFF) * D) + lane);
            unsigned u3 = *((const unsigned*)(h + (size_t)(e3[0] & 0x1FFFF) * D) + lane);
            float v0 = __int_as_float(e0[1]), v1 = __int_as_float(e1[1]);
            float v2 = __int_as_float(e2[1]), v3 = __int_as_float(e3[1]);
            a0 += v0 * __int_as_float(u0 << 16);  b0 += v0 * __int_as_float(u0 & 0xffff0000u);
            a1 += v1 * __int_as_float(u1 << 16);  b1 += v1 * __int_as_float(u1 & 0xffff0000u);
            a2 += v2 * __int_as_float(u2 << 16);  b2 += v2 * __int_as_float(u2 & 0xffff0000u);
            a3 += v3 * __int_as_float(u3 << 16);  b3 += v3 * __int_as_float(u3 & 0xffff0000u);
        }
        for (; i < e; ++i) {
            i32x2 e0 = lbuf[i];
            unsigned u0 = *((const unsigned*)(h + (size_t)(e0[0] & 0x1FFFF) * D) + lane);
            float v0 = __int_as_float(e0[1]);
            a0 += v0 * __int_as_float(u0 << 16);  b0 += v0 * __int_as_float(u0 & 0xffff0000u);
        }

        f32x2 o;
        o[0] = fmaxf((a0 + a1) + (a2 + a3), 0.0f);
        o[1] = fmaxf((b0 + b1) + (b2 + b3), 0.0f);
        __builtin_nontemporal_store(o, (f32x2*)(out + (size_t)gr * D + lane * 2));
    }
}

extern "C" void kernel_launch(void* const* d_in, const int* in_sizes, int n_in,
                              void* d_out, int out_size, void* d_ws, size_t ws_size,
                              hipStream_t stream) {
    const float* x    = (const float*)d_in[0];
    const float* w    = (const float*)d_in[1];
    const float* vals = (const float*)d_in[2];
    const int*   rows = (const int*)d_in[3];
    const int*   cols = (const int*)d_in[4];
    float*       out  = (float*)d_out;

    // ---- workspace (~39.7 MB; 51.2 MB proven available in R3) ----
    char* p = (char*)d_ws;
    __bf16* h         = (__bf16*)p;  p += (size_t)N_NODES * D * 2;      // 25.6 MB
    __bf16* WT        = (__bf16*)p;  p += (size_t)D * D * 2;            // 32 KB
    int*    counts    = (int*)p;     p += (size_t)N_NODES * 4;          // 400 KB
    int*    offsets   = (int*)p;     p += (size_t)(NR + 16) * 4;        // 402 KB
    int*    blockSums = (int*)p;     p += 2048;                         // 392 ints
    int*    coarseCur = (int*)p;     p += 2048;                         // 392 ints
    i32x2*  svcA      = (i32x2*)p;   p += (size_t)N_EDGES * 8;          // 12.8 MB

    (void)hipMemsetAsync(counts, 0, (size_t)N_NODES * sizeof(int), stream);

    hist_transpose_kernel<<<6250 + 64, 256, 0, stream>>>(rows, w, WT, counts);
    block_reduce_kernel<<<SCAN_BLOCKS, 256, 0, stream>>>(counts, blockSums);
    scan_blocksums_kernel<<<1, 512, 0, stream>>>(blockSums, coarseCur);
    scan_final_kernel<<<SCAN_BLOCKS, 256, 0, stream>>>(counts, blockSums, offsets);
    gemm_kernel<<<(N_TILES + 3) / 4, 256, 0, stream>>>(x, WT, h);
    scatterA_kernel<<<HIST_WGS, 256, 0, stream>>>(rows, cols, vals, coarseCur, svcA);
    sortsum_kernel<<<NB, 1024, 0, stream>>>(h, offsets, svcA, out);
}

// Round 10
// 229.957 us; speedup vs baseline: 1.3725x; 1.3725x over previous
//
#include <hip/hip_runtime.h>
#include <hip/hip_bf16.h>

#define N_NODES 100000
#define N_EDGES 1600000
#define D 128
#define N_TILES 6250             // N_NODES/16
#define NB 512                   // buckets
#define RPB 196                  // rows per bucket (512*196 = 100352 >= N_NODES)
#define BCAP 3584                // slab capacity: mean 3136 + 8 sigma (R9-validated margin)
#define SA_EDGES 3125            // edges per scatterA WG (512*3125 = 1.6M exact)
#define CAP 16                   // LDS staging depth per bucket

typedef __bf16 bf16x8 __attribute__((ext_vector_type(8)));
typedef float  f32x4  __attribute__((ext_vector_type(4)));
typedef float  f32x2  __attribute__((ext_vector_type(2)));
typedef int    i32x2  __attribute__((ext_vector_type(2)));

// ---- K1: W transpose (fp32 -> bf16 WT) + zero bucket cursors ----
__global__ __launch_bounds__(256) void prep_kernel(const float* __restrict__ W,
                                                   __bf16* __restrict__ WT,
                                                   int* __restrict__ bucketCnt) {
    int t = blockIdx.x * 256 + threadIdx.x;   // 16384 threads
    int k = t >> 7, n = t & 127;
    WT[n * D + k] = (__bf16)W[t];
    if (t < NB) bucketCnt[t] = 0;
}

// ---- K2: GEMM h = bf16(x) @ bf16(W) (verified since R6) ----
__global__ __launch_bounds__(256) void gemm_kernel(
        const float* __restrict__ x,
        const __bf16* __restrict__ WT,
        __bf16* __restrict__ h) {
    __shared__ __bf16 lsm[4][16][144];
    const int wave = threadIdx.x >> 6;
    const int lane = threadIdx.x & 63;
    const int tile = blockIdx.x * 4 + wave;
    if (tile >= N_TILES) return;
    const int m = lane & 15, quad = lane >> 4;
    const float* xp = x + (size_t)(tile * 16 + m) * D + quad * 8;

    f32x4 acc[8];
#pragma unroll
    for (int ct = 0; ct < 8; ++ct) acc[ct] = (f32x4)(0.0f);
#pragma unroll
    for (int kk = 0; kk < 4; ++kk) {
        f32x4 a0 = *(const f32x4*)(xp + kk * 32);
        f32x4 a1 = *(const f32x4*)(xp + kk * 32 + 4);
        bf16x8 a;
#pragma unroll
        for (int j = 0; j < 4; ++j) { a[j] = (__bf16)a0[j]; a[j + 4] = (__bf16)a1[j]; }
#pragma unroll
        for (int ct = 0; ct < 8; ++ct) {
            bf16x8 b = *(const bf16x8*)(WT + (size_t)(ct * 16 + m) * D + kk * 32 + quad * 8);
            acc[ct] = __builtin_amdgcn_mfma_f32_16x16x32_bf16(a, b, acc[ct], 0, 0, 0);
        }
    }
#pragma unroll
    for (int ct = 0; ct < 8; ++ct)
#pragma unroll
        for (int r = 0; r < 4; ++r)
            lsm[wave][quad * 4 + r][ct * 16 + m] = (__bf16)acc[ct][r];
#pragma unroll
    for (int i = 0; i < 4; ++i) {
        int rl = i * 4 + quad;
        bf16x8 vv = *(const bf16x8*)&lsm[wave][rl][m * 8];
        *(bf16x8*)(h + (size_t)(tile * 16 + rl) * D + m * 8) = vv;
    }
}

// ---- K3: LDS-staged scatter into fixed-capacity bucket slabs ----
// pack = (localRow<<17) | col, val as bits; claims via global per-bucket cursor
__global__ __launch_bounds__(256) void scatterA_kernel(
        const int* __restrict__ rows, const int* __restrict__ cols,
        const float* __restrict__ vals,
        int* __restrict__ bucketCnt, i32x2* __restrict__ svcA) {
    __shared__ i32x2 buf[NB][CAP];   // 64 KB
    __shared__ int   cnt[NB];        // 2 KB
    for (int t = threadIdx.x; t < NB; t += 256) cnt[t] = 0;
    __syncthreads();
    const int base = blockIdx.x * SA_EDGES;
    for (int it = 0; it < 13; ++it) {
        int idx = it * 256 + threadIdx.x;
        if (idx < SA_EDGES) {
            int e = base + idx;
            int r = rows[e];
            int b = r / RPB;                  // magic-mul division by 196
            int local = r - b * RPB;
            i32x2 pk;
            pk[0] = (local << 17) | cols[e];
            pk[1] = __float_as_int(vals[e]);
            int p = atomicAdd(&cnt[b], 1);
            if (p < CAP) buf[b][p] = pk;
            else {                             // rare overflow: direct claim
                int g = atomicAdd(&bucketCnt[b], 1);
                if (g < BCAP) svcA[(size_t)b * BCAP + g] = pk;
            }
        }
    }
    __syncthreads();
    for (int t = threadIdx.x; t < NB; t += 256) {
        int n = min(cnt[t], CAP);
        if (n > 0) {
            int g = atomicAdd(&bucketCnt[t], n);
            i32x2* dst = svcA + (size_t)t * BCAP;
            for (int i = 0; i < n; ++i)
                if (g + i < BCAP) dst[g + i] = buf[t][i];   // contiguous run
        }
    }
}

// ---- K4: fused local sort (hist+scan in LDS) + segmented sum + relu ----
// one 1024-thread WG per bucket; register accumulators (R7 lesson: never
// accumulate the hot fp32 sums via LDS atomics).
__global__ __launch_bounds__(1024) void sortsum_kernel(
        const __bf16* __restrict__ h, const int* __restrict__ bucketCnt,
        const i32x2* __restrict__ svcA, float* __restrict__ out) {
    __shared__ i32x2 lbuf[BCAP];     // 28 KB
    __shared__ int   lhist[256];
    __shared__ int   send[256];      // inclusive scan (row ends)
    __shared__ int   lcur[256];      // scatter cursors (row starts, mutated)
    const int b   = blockIdx.x;
    const int tid = threadIdx.x;
    const int n   = min(bucketCnt[b], BCAP);
    const i32x2* win = svcA + (size_t)b * BCAP;

    if (tid < 256) lhist[tid] = 0;
    __syncthreads();

    // load window into registers (<=4 recs/thread) + LDS histogram
    i32x2 rec0, rec1, rec2, rec3;
    const int i0 = tid, i1 = tid + 1024, i2 = tid + 2048, i3 = tid + 3072;
    if (i0 < n) { rec0 = win[i0]; atomicAdd(&lhist[((unsigned)rec0[0]) >> 17], 1); }
    if (i1 < n) { rec1 = win[i1]; atomicAdd(&lhist[((unsigned)rec1[0]) >> 17], 1); }
    if (i2 < n) { rec2 = win[i2]; atomicAdd(&lhist[((unsigned)rec2[0]) >> 17], 1); }
    if (i3 < n) { rec3 = win[i3]; atomicAdd(&lhist[((unsigned)rec3[0]) >> 17], 1); }
    __syncthreads();

    // inclusive Hillis-Steele scan over 256 (rows 196..255 are zero)
    int v = 0;
    if (tid < 256) { v = lhist[tid]; send[tid] = v; }
    __syncthreads();
    for (int d = 1; d < 256; d <<= 1) {
        int t2 = 0;
        if (tid < 256 && tid >= d) t2 = send[tid - d];
        __syncthreads();
        if (tid < 256) send[tid] += t2;
        __syncthreads();
    }
    if (tid < 256) lcur[tid] = send[tid] - v;   // exclusive starts
    __syncthreads();

    // scatter registers into row-sorted LDS
    if (i0 < n) { int rl = ((unsigned)rec0[0]) >> 17; lbuf[atomicAdd(&lcur[rl], 1)] = rec0; }
    if (i1 < n) { int rl = ((unsigned)rec1[0]) >> 17; lbuf[atomicAdd(&lcur[rl], 1)] = rec1; }
    if (i2 < n) { int rl = ((unsigned)rec2[0]) >> 17; lbuf[atomicAdd(&lcur[rl], 1)] = rec2; }
    if (i3 < n) { int rl = ((unsigned)rec3[0]) >> 17; lbuf[atomicAdd(&lcur[rl], 1)] = rec3; }
    __syncthreads();

    // per-wave register-accumulator segsum, 4-wide gather MLP
    const int wave = tid >> 6;
    const int lane = tid & 63;
    for (int rl = wave; rl < RPB; rl += 16) {
        int gr = b * RPB + rl;
        if (gr >= N_NODES) break;
        int s = rl ? send[rl - 1] : 0;
        int e = send[rl];

        float a0 = 0.f, b0 = 0.f, a1 = 0.f, b1 = 0.f;
        float a2 = 0.f, b2 = 0.f, a3 = 0.f, b3 = 0.f;
        int i = s;
        for (; i + 3 < e; i += 4) {
            i32x2 e0 = lbuf[i], e1 = lbuf[i + 1], e2 = lbuf[i + 2], e3 = lbuf[i + 3];
            unsigned u0 = *((const unsigned*)(h + (size_t)(e0[0] & 0x1FFFF) * D) + lane);
            unsigned u1 = *((const unsigned*)(h + (size_t)(e1[0] & 0x1FFFF) * D) + lane);
            unsigned u2 = *((const unsigned*)(h + (size_t)(e2[0] & 0x1FFFF) * D) + lane);
            unsigned u3 = *((const unsigned*)(h + (size_t)(e3[0] & 0x1FFFF) * D) + lane);
            float v0 = __int_as_float(e0[1]), v1 = __int_as_float(e1[1]);
            float v2 = __int_as_float(e2[1]), v3 = __int_as_float(e3[1]);
            a0 += v0 * __int_as_float(u0 << 16);  b0 += v0 * __int_as_float(u0 & 0xffff0000u);
            a1 += v1 * __int_as_float(u1 << 16);  b1 += v1 * __int_as_float(u1 & 0xffff0000u);
            a2 += v2 * __int_as_float(u2 << 16);  b2 += v2 * __int_as_float(u2 & 0xffff0000u);
            a3 += v3 * __int_as_float(u3 << 16);  b3 += v3 * __int_as_float(u3 & 0xffff0000u);
        }
        for (; i < e; ++i) {
            i32x2 e0 = lbuf[i];
            unsigned u0 = *((const unsigned*)(h + (size_t)(e0[0] & 0x1FFFF) * D) + lane);
            float v0 = __int_as_float(e0[1]);
            a0 += v0 * __int_as_float(u0 << 16);  b0 += v0 * __int_as_float(u0 & 0xffff0000u);
        }

        f32x2 o;
        o[0] = fmaxf((a0 + a1) + (a2 + a3), 0.0f);
        o[1] = fmaxf((b0 + b1) + (b2 + b3), 0.0f);
        __builtin_nontemporal_store(o, (f32x2*)(out + (size_t)gr * D + lane * 2));
    }
}

extern "C" void kernel_launch(void* const* d_in, const int* in_sizes, int n_in,
                              void* d_out, int out_size, void* d_ws, size_t ws_size,
                              hipStream_t stream) {
    const float* x    = (const float*)d_in[0];
    const float* w    = (const float*)d_in[1];
    const float* vals = (const float*)d_in[2];
    const int*   rows = (const int*)d_in[3];
    const int*   cols = (const int*)d_in[4];
    float*       out  = (float*)d_out;

    // ---- workspace (~40.3 MB) ----
    char* p = (char*)d_ws;
    __bf16* h         = (__bf16*)p;  p += (size_t)N_NODES * D * 2;          // 25.6 MB
    __bf16* WT        = (__bf16*)p;  p += (size_t)D * D * 2;                // 32 KB
    int*    bucketCnt = (int*)p;     p += 4096;                             // NB ints
    i32x2*  svcA      = (i32x2*)p;   p += (size_t)NB * BCAP * 8;            // 14.7 MB

    prep_kernel<<<64, 256, 0, stream>>>(w, WT, bucketCnt);
    gemm_kernel<<<(N_TILES + 3) / 4, 256, 0, stream>>>(x, WT, h);
    scatterA_kernel<<<NB, 256, 0, stream>>>(rows, cols, vals, bucketCnt, svcA);
    sortsum_kernel<<<NB, 1024, 0, stream>>>(h, bucketCnt, svcA, out);
}